// Round 2
// baseline (932.054 us; speedup 1.0000x reference)
//
#include <hip/hip_runtime.h>
#include <math.h>

#define NROWS  500000
#define NCHK   7813      // ceil(500000/64)
#define NSTRIP 31250     // 500000/16
#define EPSV   1e-5f

// ---- ws layout (byte offsets) ----
static const size_t SN_OFF   = 0;        // Sn      16384 f32
static const size_t P_OFF    = 65536;    // P       16384 f32
static const size_t P2_OFF   = 131072;   // P2 / gramTot
static const size_t PS_OFF   = 196608;   // PS
static const size_t W_OFF    = 262144;   // W fp32
static const size_t MEAN_OFF = 327680;   // 128 f32
static const size_t BIAS_OFF = 328192;   // 128 f32
static const size_t SCAL_OFF = 328704;   // scalars
static const size_t CS_OFF   = 393216;   // colsum partials G*128 f32 (<=512 -> 256KB)
static const size_t GRAM_OFF = 1048576;  // gram partials G*16384 f32
static const size_t GRAM_FALLBACK = 458752; // if ws too small, G=1 slice here

// ============ Kernel 1: column sums + Gram partials (pure fp32 VALU) ========
// Gram = X^T X accumulated per block over 64-row chunks staged in LDS.
// Thread t owns an 8x8 tile of the 128x128 Gram: rows i0..i0+7, cols j0..j0+7.
__global__ __launch_bounds__(256) void k_stats(const float* __restrict__ X,
        float* __restrict__ csPart, float* __restrict__ gramPart) {
    __shared__ float sX[64][132];    // padded stride: 528B, 16B-aligned rows
    __shared__ float scs[256][4];
    const int t  = threadIdx.x;
    const int i0 = (t >> 4) << 3;    // 0,8,...,120
    const int j0 = (t & 15) << 3;
    const int rr = t >> 5;           // 0..7
    const int cc = (t & 31) << 2;    // 0..124 (constant per thread)
    float acc[8][8];
    #pragma unroll
    for (int a = 0; a < 8; a++)
        #pragma unroll
        for (int b = 0; b < 8; b++) acc[a][b] = 0.f;
    float cs0 = 0.f, cs1 = 0.f, cs2 = 0.f, cs3 = 0.f;

    for (int ch = blockIdx.x; ch < NCHK; ch += gridDim.x) {
        const size_t row0 = (size_t)ch << 6;
        #pragma unroll
        for (int i = 0; i < 8; i++) {
            const int r = rr + (i << 3);          // 0..63
            const size_t row = row0 + r;
            float4 v = {0.f, 0.f, 0.f, 0.f};
            if (row < NROWS)
                v = *reinterpret_cast<const float4*>(X + row * 128 + cc);
            cs0 += v.x; cs1 += v.y; cs2 += v.z; cs3 += v.w;
            *reinterpret_cast<float4*>(&sX[r][cc]) = v;
        }
        __syncthreads();
        for (int r = 0; r < 64; r++) {
            float xi[8], xj[8];
            *reinterpret_cast<float4*>(&xi[0]) = *reinterpret_cast<const float4*>(&sX[r][i0]);
            *reinterpret_cast<float4*>(&xi[4]) = *reinterpret_cast<const float4*>(&sX[r][i0 + 4]);
            *reinterpret_cast<float4*>(&xj[0]) = *reinterpret_cast<const float4*>(&sX[r][j0]);
            *reinterpret_cast<float4*>(&xj[4]) = *reinterpret_cast<const float4*>(&sX[r][j0 + 4]);
            #pragma unroll
            for (int a = 0; a < 8; a++)
                #pragma unroll
                for (int b = 0; b < 8; b++)
                    acc[a][b] = fmaf(xi[a], xj[b], acc[a][b]);
        }
        __syncthreads();
    }
    float* gp = gramPart + (size_t)blockIdx.x * 16384;
    #pragma unroll
    for (int a = 0; a < 8; a++)
        #pragma unroll
        for (int b = 0; b < 8; b++)
            gp[(i0 + a) * 128 + (j0 + b)] = acc[a][b];
    scs[t][0] = cs0; scs[t][1] = cs1; scs[t][2] = cs2; scs[t][3] = cs3;
    __syncthreads();
    if (t < 128) {
        float s = 0.f;
        #pragma unroll
        for (int q = 0; q < 8; q++) s += scs[q * 32 + (t >> 2)][t & 3];
        csPart[(size_t)blockIdx.x * 128 + t] = s;
    }
}

// ============ Kernel 2a: deterministic tree-reduce of partials ==============
__global__ __launch_bounds__(256) void k_reduce(const float* __restrict__ gramPart,
        const float* __restrict__ csPart, float* __restrict__ gramTot,
        float* __restrict__ mean, int G) {
    const int t = threadIdx.x;
    if (blockIdx.x == 256) {           // mean block
        if (t < 128) {
            float s = 0.f;
            for (int g = 0; g < G; g++) s += csPart[(size_t)g * 128 + t];
            mean[t] = s * (1.0f / (float)NROWS);
        }
        return;
    }
    const int e = blockIdx.x * 64 + (t & 63);
    const int q = t >> 6;
    float s = 0.f;
    for (int g = q; g < G; g += 4) s += gramPart[(size_t)g * 16384 + e];
    __shared__ float red[4][64];
    red[q][t & 63] = s;
    __syncthreads();
    if (t < 64)
        gramTot[blockIdx.x * 64 + t] = red[0][t] + red[1][t] + red[2][t] + red[3][t];
}

// ============ Kernel 2b: Sigma -> Sn, rTr, P=I ===============================
__global__ __launch_bounds__(256) void k_sigma(const float* __restrict__ gramTot,
        const float* __restrict__ mean, float* __restrict__ Sn,
        float* __restrict__ P, float* __restrict__ scal) {
    const int t = threadIdx.x;
    __shared__ float rs[256];
    const float mj = mean[t & 127];
    float sig[64];
    float tr = 0.f;
    #pragma unroll
    for (int i = 0; i < 64; i++) {
        const int e = t + (i << 8);
        const int ii = e >> 7;
        float s = gramTot[e] * (1.0f / (float)NROWS) - mean[ii] * mj;
        if (ii == (e & 127)) { s += EPSV; tr += s; }
        sig[i] = s;
    }
    rs[t] = tr;
    __syncthreads();
    #pragma unroll
    for (int off = 128; off > 0; off >>= 1) {
        if (t < off) rs[t] += rs[t + off];
        __syncthreads();
    }
    const float rTr = 1.0f / rs[0];
    #pragma unroll
    for (int i = 0; i < 64; i++) {
        const int e = t + (i << 8);
        Sn[e] = sig[i] * rTr;
        P[e]  = ((e >> 7) == (e & 127)) ? 1.f : 0.f;
    }
    if (t == 0) scal[0] = sqrtf(rTr);
}

// ============ 128x128 fp32 matmul, no LDS (L2-resident operands) ============
// Block owns 16 output rows starting at r0; thread: 2 rows x 4 cols.
__device__ __forceinline__ void mm16_glb(const float* __restrict__ A,
        const float* __restrict__ B, float* __restrict__ C,
        const float* __restrict__ D, float alpha, float beta, int r0) {
    const int t  = threadIdx.x;
    const int r  = r0 + ((t >> 5) << 1);
    const int tc = (t & 31) << 2;
    float a00=0,a01=0,a02=0,a03=0, a10=0,a11=0,a12=0,a13=0;
    for (int k0 = 0; k0 < 128; k0 += 4) {
        const float4 av0 = *reinterpret_cast<const float4*>(&A[r * 128 + k0]);
        const float4 av1 = *reinterpret_cast<const float4*>(&A[(r + 1) * 128 + k0]);
        const float x0[4] = {av0.x, av0.y, av0.z, av0.w};
        const float x1[4] = {av1.x, av1.y, av1.z, av1.w};
        #pragma unroll
        for (int j = 0; j < 4; j++) {
            const float4 b = *reinterpret_cast<const float4*>(&B[(k0 + j) * 128 + tc]);
            a00 = fmaf(x0[j], b.x, a00); a01 = fmaf(x0[j], b.y, a01);
            a02 = fmaf(x0[j], b.z, a02); a03 = fmaf(x0[j], b.w, a03);
            a10 = fmaf(x1[j], b.x, a10); a11 = fmaf(x1[j], b.y, a11);
            a12 = fmaf(x1[j], b.z, a12); a13 = fmaf(x1[j], b.w, a13);
        }
    }
    const float v0[4] = {a00,a01,a02,a03};
    const float v1[4] = {a10,a11,a12,a13};
    #pragma unroll
    for (int c = 0; c < 4; c++) {
        float v = alpha * v0[c];
        if (D) v = fmaf(beta, D[r * 128 + tc + c], v);
        C[r * 128 + tc + c] = v;
    }
    #pragma unroll
    for (int c = 0; c < 4; c++) {
        float v = alpha * v1[c];
        if (D) v = fmaf(beta, D[(r + 1) * 128 + tc + c], v);
        C[(r + 1) * 128 + tc + c] = v;
    }
}

__global__ __launch_bounds__(256) void k_mm_pair(const float* __restrict__ P,
        const float* __restrict__ Sn, float* __restrict__ P2, float* __restrict__ PS) {
    const float* B = (blockIdx.y == 0) ? P : Sn;
    float* C = (blockIdx.y == 0) ? P2 : PS;
    mm16_glb(P, B, C, nullptr, 1.f, 0.f, blockIdx.x * 16);
}

__global__ __launch_bounds__(256) void k_mm_update(const float* __restrict__ P2,
        const float* __restrict__ PS, float* __restrict__ P) {
    mm16_glb(P2, PS, P, P, -0.5f, 1.5f, blockIdx.x * 16);
}

__global__ __launch_bounds__(256) void k_mm_w(const float* __restrict__ R,
        const float* __restrict__ P, float* __restrict__ W,
        const float* __restrict__ scal) {
    mm16_glb(R, P, W, nullptr, scal[0], 0.f, blockIdx.x * 16);
}

// ============ bias[d] = sum_c W[d][c]*mean[c] ================================
__global__ __launch_bounds__(128) void k_bias(const float* __restrict__ W,
        const float* __restrict__ mean, float* __restrict__ bias) {
    const int d = threadIdx.x;
    float s = 0.f;
    for (int c = 0; c < 128; c++) s += W[d * 128 + c] * mean[c];
    bias[d] = s;
}

// ============ Kernel 5: out = X * W^T - bias (pure fp32 VALU) ===============
// W^T staged in LDS (exactly 64KB). Block handles 16-row strips, grid-stride.
__global__ __launch_bounds__(256) void k_out(const float* __restrict__ X,
        const float* __restrict__ W, const float* __restrict__ bias,
        float* __restrict__ out) {
    __shared__ float sWT[128][128];  // sWT[c][d] = W[d][c]
    const int t = threadIdx.x;
    #pragma unroll
    for (int i = 0; i < 16; i++) {
        const int idx = t + (i << 8);
        const int d = idx >> 5, c4 = (idx & 31) << 2;
        const float4 v = *reinterpret_cast<const float4*>(&W[d * 128 + c4]);
        sWT[c4 + 0][d] = v.x; sWT[c4 + 1][d] = v.y;
        sWT[c4 + 2][d] = v.z; sWT[c4 + 3][d] = v.w;
    }
    __syncthreads();
    const int tr = (t >> 5) << 1;    // 0..14
    const int tc = (t & 31) << 2;    // 0..124
    const float4 bv = *reinterpret_cast<const float4*>(&bias[tc]);
    const float bb[4] = {bv.x, bv.y, bv.z, bv.w};
    for (int strip = blockIdx.x; strip < NSTRIP; strip += gridDim.x) {
        const size_t r0 = (size_t)strip * 16;
        const float* xr0 = X + (r0 + tr) * 128;
        const float* xr1 = xr0 + 128;
        float a00=0,a01=0,a02=0,a03=0, a10=0,a11=0,a12=0,a13=0;
        for (int c0 = 0; c0 < 128; c0 += 4) {
            const float4 xv0 = *reinterpret_cast<const float4*>(xr0 + c0);
            const float4 xv1 = *reinterpret_cast<const float4*>(xr1 + c0);
            const float x0[4] = {xv0.x, xv0.y, xv0.z, xv0.w};
            const float x1[4] = {xv1.x, xv1.y, xv1.z, xv1.w};
            #pragma unroll
            for (int j = 0; j < 4; j++) {
                const float4 wv = *reinterpret_cast<const float4*>(&sWT[c0 + j][tc]);
                a00 = fmaf(x0[j], wv.x, a00); a01 = fmaf(x0[j], wv.y, a01);
                a02 = fmaf(x0[j], wv.z, a02); a03 = fmaf(x0[j], wv.w, a03);
                a10 = fmaf(x1[j], wv.x, a10); a11 = fmaf(x1[j], wv.y, a11);
                a12 = fmaf(x1[j], wv.z, a12); a13 = fmaf(x1[j], wv.w, a13);
            }
        }
        const float4 o0 = {a00 - bb[0], a01 - bb[1], a02 - bb[2], a03 - bb[3]};
        const float4 o1 = {a10 - bb[0], a11 - bb[1], a12 - bb[2], a13 - bb[3]};
        *reinterpret_cast<float4*>(&out[(r0 + tr) * 128 + tc]) = o0;
        *reinterpret_cast<float4*>(&out[(r0 + tr + 1) * 128 + tc]) = o1;
    }
}

extern "C" void kernel_launch(void* const* d_in, const int* in_sizes, int n_in,
                              void* d_out, int out_size, void* d_ws, size_t ws_size,
                              hipStream_t stream) {
    const float* X = (const float*)d_in[0];
    const float* R = (const float*)d_in[1];   // running_rot[0], row-major [d][c]
    float* out = (float*)d_out;
    char* ws = (char*)d_ws;
    float* Sn     = (float*)(ws + SN_OFF);
    float* P      = (float*)(ws + P_OFF);
    float* P2     = (float*)(ws + P2_OFF);    // also gramTot
    float* PS     = (float*)(ws + PS_OFF);
    float* W      = (float*)(ws + W_OFF);
    float* mean   = (float*)(ws + MEAN_OFF);
    float* bias   = (float*)(ws + BIAS_OFF);
    float* scal   = (float*)(ws + SCAL_OFF);
    float* csPart = (float*)(ws + CS_OFF);

    int G = 512;
    size_t gramOff = GRAM_OFF;
    if (ws_size < GRAM_OFF + (size_t)G * 65536) {
        size_t avail = (ws_size > GRAM_OFF) ? (ws_size - GRAM_OFF) : 0;
        G = (int)(avail / 65536);
        if (G < 1) { G = 1; gramOff = GRAM_FALLBACK; }
        if (G > 512) G = 512;
    }
    float* gramPart = (float*)(ws + gramOff);

    k_stats<<<dim3(G), dim3(256), 0, stream>>>(X, csPart, gramPart);
    k_reduce<<<dim3(257), dim3(256), 0, stream>>>(gramPart, csPart, P2, mean, G);
    k_sigma<<<dim3(1), dim3(256), 0, stream>>>(P2, mean, Sn, P, scal);
    for (int it = 0; it < 5; ++it) {
        k_mm_pair<<<dim3(8, 2), dim3(256), 0, stream>>>(P, Sn, P2, PS);
        k_mm_update<<<dim3(8), dim3(256), 0, stream>>>(P2, PS, P);
    }
    k_mm_w<<<dim3(8), dim3(256), 0, stream>>>(R, P, W, scal);
    k_bias<<<dim3(1), dim3(128), 0, stream>>>(W, mean, bias);
    k_out<<<dim3(1024), dim3(256), 0, stream>>>(X, W, bias, out);
}

// Round 4
// 408.455 us; speedup vs baseline: 2.2819x; 2.2819x over previous
//
#include <hip/hip_runtime.h>
#include <math.h>

#define NROWS  500000
#define NCHK   7813      // ceil(500000/64)
#define EPSV   1e-5f

typedef __bf16 bf16_t;
typedef __bf16 bf16x4 __attribute__((ext_vector_type(4)));
typedef __bf16 bf16x8 __attribute__((ext_vector_type(8)));
typedef float  f32x4  __attribute__((ext_vector_type(4)));

// ---- ws layout (byte offsets) ----
static const size_t SN_OFF   = 0;        // Sn      16384 f32
static const size_t P_OFF    = 65536;    // P       16384 f32
static const size_t P2_OFF   = 131072;   // P2 / gramTot
static const size_t PS_OFF   = 196608;   // PS
static const size_t W_OFF    = 262144;   // W fp32
static const size_t WB_OFF   = 327680;   // W bf16 (32KB)
static const size_t MEAN_OFF = 360448;   // 128 f32
static const size_t BIAS_OFF = 360960;   // 128 f32
static const size_t SCAL_OFF = 361472;   // scalars
static const size_t CS_OFF   = 393216;   // colsum partials G*128 f32 (ends 655360)
static const size_t GRAM_FALLBACK = 655360; // G=1 slice if ws tiny
static const size_t GRAM_OFF = 1048576;  // gram partials G*16384 f32

// ============ Kernel 1: column sums + Gram partials (bf16 MFMA) =============
// Gram = X^T X over 64-row chunks staged in LDS (bf16), double-buffered.
// sxt row = sample (64), col = feature (128 + 8 pad -> 272B stride, 16B-mult).
// MFMA 16x16x32: A/B k-permutation cancels (same map both operands);
// D col=lane&15, row=(lane>>4)*4+reg  [m89-verified].
__global__ __launch_bounds__(256) void k_stats(const float* __restrict__ X,
        float* __restrict__ csPart, float* __restrict__ gramPart) {
    __shared__ bf16_t sxt[2][64][136];  // [buf][sample n][feature c]  (FIXED size)
    __shared__ float  scs[256][4];
    const int t    = threadIdx.x;
    const int lane = t & 63;
    const int w    = t >> 6;     // wave 0..3
    const int cg   = t & 31;     // col group (4 consecutive feature cols)
    const int rb   = t >> 5;     // 0..7
    const int cl   = lane & 15;
    const int kq   = lane >> 4;
    const int G    = gridDim.x;

    f32x4 acc[2][8];
    #pragma unroll
    for (int a = 0; a < 2; a++)
        #pragma unroll
        for (int b = 0; b < 8; b++)
            acc[a][b] = (f32x4){0.f, 0.f, 0.f, 0.f};
    float cs0 = 0.f, cs1 = 0.f, cs2 = 0.f, cs3 = 0.f;

    float4 R[8];

    auto GLOADC = [&](int ch) {
        const size_t row0 = (size_t)ch << 6;
        #pragma unroll
        for (int i = 0; i < 8; i++) {
            const size_t row = row0 + rb + (i << 3);
            R[i] = (row < NROWS)
                 ? *reinterpret_cast<const float4*>(X + row * 128 + (cg << 2))
                 : float4{0.f, 0.f, 0.f, 0.f};
        }
    };
    auto DSWRITEC = [&](int buf) {
        #pragma unroll
        for (int i = 0; i < 8; i++) {
            cs0 += R[i].x; cs1 += R[i].y; cs2 += R[i].z; cs3 += R[i].w;
            bf16x4 b4 = { (bf16_t)R[i].x, (bf16_t)R[i].y,
                          (bf16_t)R[i].z, (bf16_t)R[i].w };
            *reinterpret_cast<bf16x4*>(&sxt[buf][rb + (i << 3)][cg << 2]) = b4;
        }
    };
    auto MFMAC = [&](int buf) {
        #pragma unroll
        for (int kb = 0; kb < 2; kb++) {
            const int nb = kb * 32 + kq * 8;     // sample base for this frag
            bf16x8 fa[2];
            #pragma unroll
            for (int a = 0; a < 2; a++) {
                const int c = (w * 2 + a) * 16 + cl;
                bf16x8 f;
                #pragma unroll
                for (int j = 0; j < 8; j++) f[j] = sxt[buf][nb + j][c];
                fa[a] = f;
            }
            #pragma unroll
            for (int b = 0; b < 8; b++) {
                const int c = b * 16 + cl;
                bf16x8 fb;
                #pragma unroll
                for (int j = 0; j < 8; j++) fb[j] = sxt[buf][nb + j][c];
                acc[0][b] = __builtin_amdgcn_mfma_f32_16x16x32_bf16(fa[0], fb, acc[0][b], 0, 0, 0);
                acc[1][b] = __builtin_amdgcn_mfma_f32_16x16x32_bf16(fa[1], fb, acc[1][b], 0, 0, 0);
            }
        }
    };

    int ch0 = blockIdx.x;        // G <= 512 < NCHK: every block has work
    GLOADC(ch0);
    DSWRITEC(0);
    __syncthreads();
    for (;;) {
        const int ch1 = ch0 + G;
        const bool v1 = ch1 < NCHK;
        if (v1) GLOADC(ch1);       // issue loads early (hide under MFMA)
        MFMAC(0);
        if (v1) DSWRITEC(1);
        __syncthreads();
        if (!v1) break;
        const int ch2 = ch1 + G;
        const bool v2 = ch2 < NCHK;
        if (v2) GLOADC(ch2);
        MFMAC(1);
        if (v2) DSWRITEC(0);
        __syncthreads();
        if (!v2) break;
        ch0 = ch2;
    }

    float* gp = gramPart + (size_t)blockIdx.x * 16384;
    #pragma unroll
    for (int a = 0; a < 2; a++)
        #pragma unroll
        for (int b = 0; b < 8; b++)
            #pragma unroll
            for (int r = 0; r < 4; r++) {
                const int row = (w * 2 + a) * 16 + kq * 4 + r;
                const int col = b * 16 + cl;
                gp[row * 128 + col] = acc[a][b][r];
            }
    scs[t][0] = cs0; scs[t][1] = cs1; scs[t][2] = cs2; scs[t][3] = cs3;
    __syncthreads();
    if (t < 128) {
        float s = 0.f;
        #pragma unroll
        for (int q = 0; q < 8; q++) s += scs[q * 32 + (t >> 2)][t & 3];
        csPart[(size_t)blockIdx.x * 128 + t] = s;
    }
}

// ============ Kernel 2a: deterministic tree-reduce of partials ==============
__global__ __launch_bounds__(256) void k_reduce(const float* __restrict__ gramPart,
        const float* __restrict__ csPart, float* __restrict__ gramTot,
        float* __restrict__ mean, int G) {
    const int t = threadIdx.x;
    if (blockIdx.x == 256) {           // mean block
        if (t < 128) {
            float s = 0.f;
            for (int g = 0; g < G; g++) s += csPart[(size_t)g * 128 + t];
            mean[t] = s * (1.0f / (float)NROWS);
        }
        return;
    }
    const int e = blockIdx.x * 64 + (t & 63);
    const int q = t >> 6;
    float s = 0.f;
    for (int g = q; g < G; g += 4) s += gramPart[(size_t)g * 16384 + e];
    __shared__ float red[4][64];
    red[q][t & 63] = s;
    __syncthreads();
    if (t < 64)
        gramTot[blockIdx.x * 64 + t] = red[0][t] + red[1][t] + red[2][t] + red[3][t];
}

// ============ Kernel 2b: Sigma -> Sn, rTr, P=I ===============================
__global__ __launch_bounds__(256) void k_sigma(const float* __restrict__ gramTot,
        const float* __restrict__ mean, float* __restrict__ Sn,
        float* __restrict__ P, float* __restrict__ scal) {
    const int t = threadIdx.x;
    __shared__ float rs[256];
    const float mj = mean[t & 127];
    float sig[64];
    float tr = 0.f;
    #pragma unroll
    for (int i = 0; i < 64; i++) {
        const int e = t + (i << 8);
        const int ii = e >> 7;
        float s = gramTot[e] * (1.0f / (float)NROWS) - mean[ii] * mj;
        if (ii == (e & 127)) { s += EPSV; tr += s; }
        sig[i] = s;
    }
    rs[t] = tr;
    __syncthreads();
    #pragma unroll
    for (int off = 128; off > 0; off >>= 1) {
        if (t < off) rs[t] += rs[t + off];
        __syncthreads();
    }
    const float rTr = 1.0f / rs[0];
    #pragma unroll
    for (int i = 0; i < 64; i++) {
        const int e = t + (i << 8);
        Sn[e] = sig[i] * rTr;
        P[e]  = ((e >> 7) == (e & 127)) ? 1.f : 0.f;
    }
    if (t == 0) scal[0] = sqrtf(rTr);
}

// ============ 128x128 fp32 matmul, no LDS (L2-resident operands) ============
__device__ __forceinline__ void mm16_glb(const float* __restrict__ A,
        const float* __restrict__ B, float* __restrict__ C,
        const float* __restrict__ D, float alpha, float beta,
        bf16_t* __restrict__ Cb, int r0) {
    const int t  = threadIdx.x;
    const int r  = r0 + ((t >> 5) << 1);
    const int tc = (t & 31) << 2;
    float a00=0,a01=0,a02=0,a03=0, a10=0,a11=0,a12=0,a13=0;
    for (int k0 = 0; k0 < 128; k0 += 4) {
        const float4 av0 = *reinterpret_cast<const float4*>(&A[r * 128 + k0]);
        const float4 av1 = *reinterpret_cast<const float4*>(&A[(r + 1) * 128 + k0]);
        const float x0[4] = {av0.x, av0.y, av0.z, av0.w};
        const float x1[4] = {av1.x, av1.y, av1.z, av1.w};
        #pragma unroll
        for (int j = 0; j < 4; j++) {
            const float4 b = *reinterpret_cast<const float4*>(&B[(k0 + j) * 128 + tc]);
            a00 = fmaf(x0[j], b.x, a00); a01 = fmaf(x0[j], b.y, a01);
            a02 = fmaf(x0[j], b.z, a02); a03 = fmaf(x0[j], b.w, a03);
            a10 = fmaf(x1[j], b.x, a10); a11 = fmaf(x1[j], b.y, a11);
            a12 = fmaf(x1[j], b.z, a12); a13 = fmaf(x1[j], b.w, a13);
        }
    }
    const float v0[4] = {a00,a01,a02,a03};
    const float v1[4] = {a10,a11,a12,a13};
    #pragma unroll
    for (int c = 0; c < 4; c++) {
        float v = alpha * v0[c];
        if (D) v = fmaf(beta, D[r * 128 + tc + c], v);
        C[r * 128 + tc + c] = v;
        if (Cb) Cb[r * 128 + tc + c] = (bf16_t)v;
    }
    #pragma unroll
    for (int c = 0; c < 4; c++) {
        float v = alpha * v1[c];
        if (D) v = fmaf(beta, D[(r + 1) * 128 + tc + c], v);
        C[(r + 1) * 128 + tc + c] = v;
        if (Cb) Cb[(r + 1) * 128 + tc + c] = (bf16_t)v;
    }
}

__global__ __launch_bounds__(256) void k_mm_pair(const float* __restrict__ P,
        const float* __restrict__ Sn, float* __restrict__ P2, float* __restrict__ PS) {
    const float* B = (blockIdx.y == 0) ? P : Sn;
    float* C = (blockIdx.y == 0) ? P2 : PS;
    mm16_glb(P, B, C, nullptr, 1.f, 0.f, nullptr, blockIdx.x * 16);
}

__global__ __launch_bounds__(256) void k_mm_update(const float* __restrict__ P2,
        const float* __restrict__ PS, float* __restrict__ P) {
    mm16_glb(P2, PS, P, P, -0.5f, 1.5f, nullptr, blockIdx.x * 16);
}

__global__ __launch_bounds__(256) void k_mm_w(const float* __restrict__ R,
        const float* __restrict__ P, float* __restrict__ W,
        bf16_t* __restrict__ Wb, const float* __restrict__ scal) {
    mm16_glb(R, P, W, nullptr, scal[0], 0.f, Wb, blockIdx.x * 16);
}

// ============ bias[d] = sum_c W[d][c]*mean[c] ================================
__global__ __launch_bounds__(128) void k_bias(const float* __restrict__ W,
        const float* __restrict__ mean, float* __restrict__ bias) {
    const int d = threadIdx.x;
    float s = 0.f;
    for (int c = 0; c < 128; c++) s += W[d * 128 + c] * mean[c];
    bias[d] = s;
}

// ============ Kernel 5: out = X * W^T - bias (bf16 MFMA, split-X) ===========
// W (bf16) in LDS [128][128+8 pad]; X loaded fp32, split hi/lo bf16.
// Register double-buffer: prefetch tile t+G while computing tile t.
__global__ __launch_bounds__(256) void k_out(const float* __restrict__ X,
        const bf16_t* __restrict__ Wb, const float* __restrict__ bias,
        float* __restrict__ out) {
    __shared__ bf16_t sW[128][136];  // FIXED size: 272B stride, 16B-mult
    __shared__ float sBias[128];
    const int t = threadIdx.x;
    #pragma unroll
    for (int i = 0; i < 16; i++) {
        const int idx = (t + (i << 8)) << 2;   // 16384 elems, 4 per thread-step
        *reinterpret_cast<bf16x4*>(&sW[idx >> 7][idx & 127]) =
            *reinterpret_cast<const bf16x4*>(&Wb[idx]);
    }
    if (t < 128) sBias[t] = bias[t];
    __syncthreads();
    const int w = t >> 6, lane = t & 63;
    const int cl = lane & 15, kq = lane >> 4;
    const int G = gridDim.x;

    float4 A0[8], A1[8];

    auto GLOAD = [&](int tl, float4 (&B)[8]) {
        const size_t rowb = (size_t)tl * 64 + w * 16;
        const bool v = rowb < NROWS;          // wave-uniform (NROWS%16==0)
        const float* xr = X + (rowb + cl) * 128;
        #pragma unroll
        for (int kb = 0; kb < 4; kb++) {
            B[2*kb]   = v ? *reinterpret_cast<const float4*>(xr + kb*32 + kq*8)
                          : float4{0.f,0.f,0.f,0.f};
            B[2*kb+1] = v ? *reinterpret_cast<const float4*>(xr + kb*32 + kq*8 + 4)
                          : float4{0.f,0.f,0.f,0.f};
        }
    };
    auto COMPUTE = [&](int tl, const float4 (&B)[8]) {
        const size_t rowbase = (size_t)tl * 64 + w * 16;
        if (rowbase >= NROWS) return;
        bf16x8 ah[4], al[4];
        #pragma unroll
        for (int kb = 0; kb < 4; kb++) {
            const float4 v0 = B[2*kb], v1 = B[2*kb+1];
            const float xv[8] = {v0.x, v0.y, v0.z, v0.w, v1.x, v1.y, v1.z, v1.w};
            bf16x8 h, l;
            #pragma unroll
            for (int j = 0; j < 8; j++) {
                h[j] = (bf16_t)xv[j];
                l[j] = (bf16_t)(xv[j] - (float)h[j]);
            }
            ah[kb] = h; al[kb] = l;
        }
        #pragma unroll
        for (int ct = 0; ct < 8; ct++) {
            f32x4 acc = (f32x4){0.f, 0.f, 0.f, 0.f};
            const int d = ct * 16 + cl;
            #pragma unroll
            for (int kb = 0; kb < 4; kb++) {
                const bf16x8 bf = *reinterpret_cast<const bf16x8*>(&sW[d][kb*32 + kq*8]);
                acc = __builtin_amdgcn_mfma_f32_16x16x32_bf16(al[kb], bf, acc, 0, 0, 0);
                acc = __builtin_amdgcn_mfma_f32_16x16x32_bf16(ah[kb], bf, acc, 0, 0, 0);
            }
            const float bc = sBias[d];
            #pragma unroll
            for (int r = 0; r < 4; r++)
                out[(rowbase + kq*4 + r) * 128 + d] = acc[r] - bc;
        }
    };

    int t0 = blockIdx.x;
    if (t0 >= NCHK) return;
    GLOAD(t0, A0);
    for (;;) {
        const int t1 = t0 + G;
        if (t1 < NCHK) GLOAD(t1, A1);   // prefetch next while computing cur
        COMPUTE(t0, A0);
        if (t1 >= NCHK) break;
        const int t2 = t1 + G;
        if (t2 < NCHK) GLOAD(t2, A0);
        COMPUTE(t1, A1);
        if (t2 >= NCHK) break;
        t0 = t2;
    }
}

extern "C" void kernel_launch(void* const* d_in, const int* in_sizes, int n_in,
                              void* d_out, int out_size, void* d_ws, size_t ws_size,
                              hipStream_t stream) {
    const float* X = (const float*)d_in[0];
    const float* R = (const float*)d_in[1];   // running_rot[0], row-major [d][c]
    float* out = (float*)d_out;
    char* ws = (char*)d_ws;
    float*  Sn     = (float*)(ws + SN_OFF);
    float*  P      = (float*)(ws + P_OFF);
    float*  P2     = (float*)(ws + P2_OFF);    // also gramTot
    float*  PS     = (float*)(ws + PS_OFF);
    float*  W      = (float*)(ws + W_OFF);
    bf16_t* Wb     = (bf16_t*)(ws + WB_OFF);
    float*  mean   = (float*)(ws + MEAN_OFF);
    float*  bias   = (float*)(ws + BIAS_OFF);
    float*  scal   = (float*)(ws + SCAL_OFF);
    float*  csPart = (float*)(ws + CS_OFF);

    int G = 512;
    size_t gramOff = GRAM_OFF;
    if (ws_size < GRAM_OFF + (size_t)G * 65536) {
        size_t avail = (ws_size > GRAM_OFF) ? (ws_size - GRAM_OFF) : 0;
        G = (int)(avail / 65536);
        if (G < 1) { G = 1; gramOff = GRAM_FALLBACK; }
        if (G > 512) G = 512;
    }
    float* gramPart = (float*)(ws + gramOff);

    k_stats<<<dim3(G), dim3(256), 0, stream>>>(X, csPart, gramPart);
    k_reduce<<<dim3(257), dim3(256), 0, stream>>>(gramPart, csPart, P2, mean, G);
    k_sigma<<<dim3(1), dim3(256), 0, stream>>>(P2, mean, Sn, P, scal);
    for (int it = 0; it < 5; ++it) {
        k_mm_pair<<<dim3(8, 2), dim3(256), 0, stream>>>(P, Sn, P2, PS);
        k_mm_update<<<dim3(8), dim3(256), 0, stream>>>(P2, PS, P);
    }
    k_mm_w<<<dim3(8), dim3(256), 0, stream>>>(R, P, W, Wb, scal);
    k_bias<<<dim3(1), dim3(128), 0, stream>>>(W, mean, bias);
    k_out<<<dim3(2048), dim3(256), 0, stream>>>(X, Wb, bias, out);
}

// Round 5
// 315.099 us; speedup vs baseline: 2.9580x; 1.2963x over previous
//
#include <hip/hip_runtime.h>
#include <math.h>

#define NROWS  500000
#define NCHK   7813      // ceil(500000/64)
#define EPSV   1e-5f

typedef __bf16 bf16_t;
typedef __bf16 bf16x4 __attribute__((ext_vector_type(4)));
typedef __bf16 bf16x8 __attribute__((ext_vector_type(8)));
typedef float  f32x4  __attribute__((ext_vector_type(4)));

// ---- ws layout (byte offsets) ----
static const size_t SN_OFF   = 0;        // (spare)
static const size_t P_OFF    = 65536;    // (spare)
static const size_t P2_OFF   = 131072;   // gramTot 16384 f32
static const size_t PS_OFF   = 196608;   // (spare)
static const size_t W_OFF    = 262144;   // (spare)
static const size_t WB_OFF   = 327680;   // W bf16 (32KB)
static const size_t MEAN_OFF = 360448;   // 128 f32
static const size_t BIAS_OFF = 360960;   // 128 f32
static const size_t SCAL_OFF = 361472;   // scalars (spare)
static const size_t CS_OFF   = 393216;   // colsum partials G*128 f32 (ends 655360)
static const size_t GRAM_FALLBACK = 655360; // G=1 slice if ws tiny
static const size_t GRAM_OFF = 1048576;  // gram partials G*16384 f32

// ============ Kernel 1: column sums + Gram partials (bf16 MFMA) =============
// UNCHANGED from round 4 (verified). Gram = X^T X over 64-row LDS chunks.
__global__ __launch_bounds__(256) void k_stats(const float* __restrict__ X,
        float* __restrict__ csPart, float* __restrict__ gramPart) {
    __shared__ bf16_t sxt[2][64][136];
    __shared__ float  scs[256][4];
    const int t    = threadIdx.x;
    const int lane = t & 63;
    const int w    = t >> 6;
    const int cg   = t & 31;
    const int rb   = t >> 5;
    const int cl   = lane & 15;
    const int kq   = lane >> 4;
    const int G    = gridDim.x;

    f32x4 acc[2][8];
    #pragma unroll
    for (int a = 0; a < 2; a++)
        #pragma unroll
        for (int b = 0; b < 8; b++)
            acc[a][b] = (f32x4){0.f, 0.f, 0.f, 0.f};
    float cs0 = 0.f, cs1 = 0.f, cs2 = 0.f, cs3 = 0.f;

    float4 R[8];

    auto GLOADC = [&](int ch) {
        const size_t row0 = (size_t)ch << 6;
        #pragma unroll
        for (int i = 0; i < 8; i++) {
            const size_t row = row0 + rb + (i << 3);
            R[i] = (row < NROWS)
                 ? *reinterpret_cast<const float4*>(X + row * 128 + (cg << 2))
                 : float4{0.f, 0.f, 0.f, 0.f};
        }
    };
    auto DSWRITEC = [&](int buf) {
        #pragma unroll
        for (int i = 0; i < 8; i++) {
            cs0 += R[i].x; cs1 += R[i].y; cs2 += R[i].z; cs3 += R[i].w;
            bf16x4 b4 = { (bf16_t)R[i].x, (bf16_t)R[i].y,
                          (bf16_t)R[i].z, (bf16_t)R[i].w };
            *reinterpret_cast<bf16x4*>(&sxt[buf][rb + (i << 3)][cg << 2]) = b4;
        }
    };
    auto MFMAC = [&](int buf) {
        #pragma unroll
        for (int kb = 0; kb < 2; kb++) {
            const int nb = kb * 32 + kq * 8;
            bf16x8 fa[2];
            #pragma unroll
            for (int a = 0; a < 2; a++) {
                const int c = (w * 2 + a) * 16 + cl;
                bf16x8 f;
                #pragma unroll
                for (int j = 0; j < 8; j++) f[j] = sxt[buf][nb + j][c];
                fa[a] = f;
            }
            #pragma unroll
            for (int b = 0; b < 8; b++) {
                const int c = b * 16 + cl;
                bf16x8 fb;
                #pragma unroll
                for (int j = 0; j < 8; j++) fb[j] = sxt[buf][nb + j][c];
                acc[0][b] = __builtin_amdgcn_mfma_f32_16x16x32_bf16(fa[0], fb, acc[0][b], 0, 0, 0);
                acc[1][b] = __builtin_amdgcn_mfma_f32_16x16x32_bf16(fa[1], fb, acc[1][b], 0, 0, 0);
            }
        }
    };

    int ch0 = blockIdx.x;
    GLOADC(ch0);
    DSWRITEC(0);
    __syncthreads();
    for (;;) {
        const int ch1 = ch0 + G;
        const bool v1 = ch1 < NCHK;
        if (v1) GLOADC(ch1);
        MFMAC(0);
        if (v1) DSWRITEC(1);
        __syncthreads();
        if (!v1) break;
        const int ch2 = ch1 + G;
        const bool v2 = ch2 < NCHK;
        if (v2) GLOADC(ch2);
        MFMAC(1);
        if (v2) DSWRITEC(0);
        __syncthreads();
        if (!v2) break;
        ch0 = ch2;
    }

    float* gp = gramPart + (size_t)blockIdx.x * 16384;
    #pragma unroll
    for (int a = 0; a < 2; a++)
        #pragma unroll
        for (int b = 0; b < 8; b++)
            #pragma unroll
            for (int r = 0; r < 4; r++) {
                const int row = (w * 2 + a) * 16 + kq * 4 + r;
                const int col = b * 16 + cl;
                gp[row * 128 + col] = acc[a][b][r];
            }
    scs[t][0] = cs0; scs[t][1] = cs1; scs[t][2] = cs2; scs[t][3] = cs3;
    __syncthreads();
    if (t < 128) {
        float s = 0.f;
        #pragma unroll
        for (int q = 0; q < 8; q++) s += scs[q * 32 + (t >> 2)][t & 3];
        csPart[(size_t)blockIdx.x * 128 + t] = s;
    }
}

// ============ Kernel 2: deterministic tree-reduce of partials ===============
__global__ __launch_bounds__(256) void k_reduce(const float* __restrict__ gramPart,
        const float* __restrict__ csPart, float* __restrict__ gramTot,
        float* __restrict__ mean, int G) {
    const int t = threadIdx.x;
    if (blockIdx.x == 256) {
        if (t < 128) {
            float s = 0.f;
            for (int g = 0; g < G; g++) s += csPart[(size_t)g * 128 + t];
            mean[t] = s * (1.0f / (float)NROWS);
        }
        return;
    }
    const int e = blockIdx.x * 64 + (t & 63);
    const int q = t >> 6;
    float s = 0.f;
    for (int g = q; g < G; g += 4) s += gramPart[(size_t)g * 16384 + e];
    __shared__ float red[4][64];
    red[q][t & 63] = s;
    __syncthreads();
    if (t < 64)
        gramTot[blockIdx.x * 64 + t] = red[0][t] + red[1][t] + red[2][t] + red[3][t];
}

// ============ Kernel 3: fused Sigma->Sn, Newton-Schulz x5, W, bias ==========
// Single block, 512 threads = 8 waves; wave w owns output band rows 16w..16w+15.
// All NS matrices are symmetric (P = polynomial in Sn), so MFMA B-frags are
// row-major reads. LDS: Ph,Pl (split-bf16 state), Sn, TT = 4 x 32KB = 128 KiB.
// k-XOR swizzle (k ^ ((row&7)<<3)) => conflict-free b128 frag reads.
__global__ __launch_bounds__(512) void k_ns(const float* __restrict__ gramTot,
        const float* __restrict__ mean, const float* __restrict__ Rg,
        bf16_t* __restrict__ Wb, float* __restrict__ bias) {
    __shared__ bf16_t sPh[16384], sPl[16384], sSn[16384], sTT[16384];
    const int t = threadIdx.x;
    const int w = t >> 6, lane = t & 63;
    const int cl = lane & 15, kq = lane >> 4;

    // ---- phase 0: Sigma, trace, Sn (bf16), P0 = 1.5I - 0.5*Sn (split) ----
    float sig[32];
    float tr = 0.f;
    #pragma unroll
    for (int i = 0; i < 32; i++) {
        const int e = t + (i << 9);
        const int r = e >> 7, c = e & 127;
        float s = gramTot[e] * (1.0f / (float)NROWS) - mean[r] * mean[c];
        if (r == c) { s += EPSV; tr += s; }
        sig[i] = s;
    }
    float* rs = reinterpret_cast<float*>(sTT);   // alias TT as f32 scratch
    rs[t] = tr;
    __syncthreads();
    #pragma unroll
    for (int off = 256; off > 0; off >>= 1) {
        if (t < off) rs[t] += rs[t + off];
        __syncthreads();
    }
    const float rTr = 1.0f / rs[0];
    __syncthreads();                              // rs read done before TT reuse
    #pragma unroll
    for (int i = 0; i < 32; i++) {
        const int e = t + (i << 9);
        const int r = e >> 7, c = e & 127;
        const int ix = r * 128 + (c ^ ((r & 7) << 3));
        const float snv = sig[i] * rTr;
        sSn[ix] = (bf16_t)snv;
        const float p0 = ((r == c) ? 1.5f : 0.f) - 0.5f * snv;
        const bf16_t ph = (bf16_t)p0;
        sPh[ix] = ph;
        sPl[ix] = (bf16_t)(p0 - (float)ph);
    }
    __syncthreads();

    // D = P * B^T (B symmetric): A = band-w rows of P (split), B rows from Bm.
    f32x4 acc[8];
    auto NSMM = [&](const bf16_t* __restrict__ Bm) {
        #pragma unroll
        for (int ct = 0; ct < 8; ct++) acc[ct] = (f32x4){0.f, 0.f, 0.f, 0.f};
        const int ra = w * 16 + cl;
        #pragma unroll
        for (int kb = 0; kb < 4; kb++) {
            const int k0 = kb * 32 + kq * 8;
            const int ia = ra * 128 + (k0 ^ ((ra & 7) << 3));
            const bf16x8 ah = *reinterpret_cast<const bf16x8*>(&sPh[ia]);
            const bf16x8 al = *reinterpret_cast<const bf16x8*>(&sPl[ia]);
            #pragma unroll
            for (int ct = 0; ct < 8; ct++) {
                const int rb = ct * 16 + cl;
                const bf16x8 bb = *reinterpret_cast<const bf16x8*>(
                    &Bm[rb * 128 + (k0 ^ ((rb & 7) << 3))]);
                acc[ct] = __builtin_amdgcn_mfma_f32_16x16x32_bf16(ah, bb, acc[ct], 0, 0, 0);
                acc[ct] = __builtin_amdgcn_mfma_f32_16x16x32_bf16(al, bb, acc[ct], 0, 0, 0);
            }
        }
    };
    auto WRT = [&](bf16_t* __restrict__ D) {
        #pragma unroll
        for (int ct = 0; ct < 8; ct++)
            #pragma unroll
            for (int r = 0; r < 4; r++) {
                const int ro = w * 16 + kq * 4 + r, co = ct * 16 + cl;
                D[ro * 128 + (co ^ ((ro & 7) << 3))] = (bf16_t)acc[ct][r];
            }
    };

    // ---- 4 full NS iterations (iter 1 folded into P0) ----
    for (int it = 0; it < 4; it++) {
        NSMM(sSn);               // T = P*Sn
        WRT(sTT);
        __syncthreads();
        NSMM(sTT);               // U = P*T
        __syncthreads();         // all waves done reading TT
        WRT(sTT);                // TT <- U
        __syncthreads();
        NSMM(sTT);               // D = P*U = P^3*Sn
        // P <- 1.5P - 0.5D (band-local, in place; P never a B-operand in NS)
        #pragma unroll
        for (int ct = 0; ct < 8; ct++)
            #pragma unroll
            for (int r = 0; r < 4; r++) {
                const int ro = w * 16 + kq * 4 + r, co = ct * 16 + cl;
                const int ix = ro * 128 + (co ^ ((ro & 7) << 3));
                const float pold = (float)sPh[ix] + (float)sPl[ix];
                const float pn = 1.5f * pold - 0.5f * acc[ct][r];
                const bf16_t ph = (bf16_t)pn;
                sPh[ix] = ph;
                sPl[ix] = (bf16_t)(pn - (float)ph);
            }
        __syncthreads();
    }

    // ---- W = R * P * sqrt(rTr); Wb (bf16) + bias = W*mean ----
    const float scal = sqrtf(rTr);
    #pragma unroll
    for (int ct = 0; ct < 8; ct++) acc[ct] = (f32x4){0.f, 0.f, 0.f, 0.f};
    const int ra = w * 16 + cl;
    #pragma unroll
    for (int kb = 0; kb < 4; kb++) {
        const int k0 = kb * 32 + kq * 8;
        const float4 rv0 = *reinterpret_cast<const float4*>(&Rg[ra * 128 + k0]);
        const float4 rv1 = *reinterpret_cast<const float4*>(&Rg[ra * 128 + k0 + 4]);
        const float rv[8] = {rv0.x, rv0.y, rv0.z, rv0.w, rv1.x, rv1.y, rv1.z, rv1.w};
        bf16x8 ah, al;
        #pragma unroll
        for (int j = 0; j < 8; j++) {
            ah[j] = (bf16_t)rv[j];
            al[j] = (bf16_t)(rv[j] - (float)ah[j]);
        }
        #pragma unroll
        for (int ct = 0; ct < 8; ct++) {
            const int rb = ct * 16 + cl;
            const int ib = rb * 128 + (k0 ^ ((rb & 7) << 3));
            const bf16x8 bh = *reinterpret_cast<const bf16x8*>(&sPh[ib]);
            const bf16x8 bl = *reinterpret_cast<const bf16x8*>(&sPl[ib]);
            acc[ct] = __builtin_amdgcn_mfma_f32_16x16x32_bf16(ah, bh, acc[ct], 0, 0, 0);
            acc[ct] = __builtin_amdgcn_mfma_f32_16x16x32_bf16(al, bh, acc[ct], 0, 0, 0);
            acc[ct] = __builtin_amdgcn_mfma_f32_16x16x32_bf16(ah, bl, acc[ct], 0, 0, 0);
        }
    }
    float pb[4] = {0.f, 0.f, 0.f, 0.f};
    #pragma unroll
    for (int ct = 0; ct < 8; ct++) {
        const float mv = mean[ct * 16 + cl];
        #pragma unroll
        for (int r = 0; r < 4; r++) {
            const float wv = acc[ct][r] * scal;
            Wb[(w * 16 + kq * 4 + r) * 128 + ct * 16 + cl] = (bf16_t)wv;
            pb[r] += wv * mv;
        }
    }
    #pragma unroll
    for (int r = 0; r < 4; r++) {
        float v = pb[r];
        v += __shfl_xor(v, 1);
        v += __shfl_xor(v, 2);
        v += __shfl_xor(v, 4);
        v += __shfl_xor(v, 8);
        if (cl == 0) bias[w * 16 + kq * 4 + r] = v;
    }
}

// ============ Kernel 4: out = X * W^T - bias (bf16 MFMA, split-X) ===========
// UNCHANGED from round 4 (verified).
__global__ __launch_bounds__(256) void k_out(const float* __restrict__ X,
        const bf16_t* __restrict__ Wb, const float* __restrict__ bias,
        float* __restrict__ out) {
    __shared__ bf16_t sW[128][136];
    __shared__ float sBias[128];
    const int t = threadIdx.x;
    #pragma unroll
    for (int i = 0; i < 16; i++) {
        const int idx = (t + (i << 8)) << 2;
        *reinterpret_cast<bf16x4*>(&sW[idx >> 7][idx & 127]) =
            *reinterpret_cast<const bf16x4*>(&Wb[idx]);
    }
    if (t < 128) sBias[t] = bias[t];
    __syncthreads();
    const int w = t >> 6, lane = t & 63;
    const int cl = lane & 15, kq = lane >> 4;
    const int G = gridDim.x;

    float4 A0[8], A1[8];

    auto GLOAD = [&](int tl, float4 (&B)[8]) {
        const size_t rowb = (size_t)tl * 64 + w * 16;
        const bool v = rowb < NROWS;
        const float* xr = X + (rowb + cl) * 128;
        #pragma unroll
        for (int kb = 0; kb < 4; kb++) {
            B[2*kb]   = v ? *reinterpret_cast<const float4*>(xr + kb*32 + kq*8)
                          : float4{0.f,0.f,0.f,0.f};
            B[2*kb+1] = v ? *reinterpret_cast<const float4*>(xr + kb*32 + kq*8 + 4)
                          : float4{0.f,0.f,0.f,0.f};
        }
    };
    auto COMPUTE = [&](int tl, const float4 (&B)[8]) {
        const size_t rowbase = (size_t)tl * 64 + w * 16;
        if (rowbase >= NROWS) return;
        bf16x8 ah[4], al[4];
        #pragma unroll
        for (int kb = 0; kb < 4; kb++) {
            const float4 v0 = B[2*kb], v1 = B[2*kb+1];
            const float xv[8] = {v0.x, v0.y, v0.z, v0.w, v1.x, v1.y, v1.z, v1.w};
            bf16x8 h, l;
            #pragma unroll
            for (int j = 0; j < 8; j++) {
                h[j] = (bf16_t)xv[j];
                l[j] = (bf16_t)(xv[j] - (float)h[j]);
            }
            ah[kb] = h; al[kb] = l;
        }
        #pragma unroll
        for (int ct = 0; ct < 8; ct++) {
            f32x4 acc = (f32x4){0.f, 0.f, 0.f, 0.f};
            const int d = ct * 16 + cl;
            #pragma unroll
            for (int kb = 0; kb < 4; kb++) {
                const bf16x8 bf = *reinterpret_cast<const bf16x8*>(&sW[d][kb*32 + kq*8]);
                acc = __builtin_amdgcn_mfma_f32_16x16x32_bf16(al[kb], bf, acc, 0, 0, 0);
                acc = __builtin_amdgcn_mfma_f32_16x16x32_bf16(ah[kb], bf, acc, 0, 0, 0);
            }
            const float bc = sBias[d];
            #pragma unroll
            for (int r = 0; r < 4; r++)
                out[(rowbase + kq*4 + r) * 128 + d] = acc[r] - bc;
        }
    };

    int t0 = blockIdx.x;
    if (t0 >= NCHK) return;
    GLOAD(t0, A0);
    for (;;) {
        const int t1 = t0 + G;
        if (t1 < NCHK) GLOAD(t1, A1);
        COMPUTE(t0, A0);
        if (t1 >= NCHK) break;
        const int t2 = t1 + G;
        if (t2 < NCHK) GLOAD(t2, A0);
        COMPUTE(t1, A1);
        if (t2 >= NCHK) break;
        t0 = t2;
    }
}

extern "C" void kernel_launch(void* const* d_in, const int* in_sizes, int n_in,
                              void* d_out, int out_size, void* d_ws, size_t ws_size,
                              hipStream_t stream) {
    const float* X = (const float*)d_in[0];
    const float* R = (const float*)d_in[1];   // running_rot[0], row-major [d][c]
    float* out = (float*)d_out;
    char* ws = (char*)d_ws;
    float*  gramTot = (float*)(ws + P2_OFF);
    bf16_t* Wb      = (bf16_t*)(ws + WB_OFF);
    float*  mean    = (float*)(ws + MEAN_OFF);
    float*  bias    = (float*)(ws + BIAS_OFF);
    float*  csPart  = (float*)(ws + CS_OFF);

    int G = 512;
    size_t gramOff = GRAM_OFF;
    if (ws_size < GRAM_OFF + (size_t)G * 65536) {
        size_t avail = (ws_size > GRAM_OFF) ? (ws_size - GRAM_OFF) : 0;
        G = (int)(avail / 65536);
        if (G < 1) { G = 1; gramOff = GRAM_FALLBACK; }
        if (G > 512) G = 512;
    }
    float* gramPart = (float*)(ws + gramOff);

    k_stats<<<dim3(G), dim3(256), 0, stream>>>(X, csPart, gramPart);
    k_reduce<<<dim3(257), dim3(256), 0, stream>>>(gramPart, csPart, gramTot, mean, G);
    k_ns<<<dim3(1), dim3(512), 0, stream>>>(gramTot, mean, R, Wb, bias);
    k_out<<<dim3(2048), dim3(256), 0, stream>>>(X, Wb, bias, out);
}